// Round 4
// baseline (410.028 us; speedup 1.0000x reference)
//
#include <hip/hip_runtime.h>
#include <hip/hip_bf16.h>

// EgoAttentionNetwork: B=8192, E=64, F_IN=7, D=64, H=4, HD=16.  fp32 in/out.
// Round 4: transaction diet. Round-3 analysis: bound by LDS-unit + L1-scatter
// transactions (~11k cyc/batch-block), not VALU issue.
//   - WkT precomputed into d_ws by prologue kernel -> kq loads coalesced
//     (was 16 loads x 64 cache lines each = ~4k L1 txns/batch-block).
//   - P1 x operands via wave-uniform scalar loads (readfirstlane'd wave idx)
//     -> xbuf LDS staging + 448 ds_read_b32/batch-block removed.
// Structure otherwise = round 3: MFMA layer-2, 2 barriers/batch, rotating
// leader wave for the serial 1-row chains, 4 blocks/CU.

typedef __attribute__((ext_vector_type(8))) short short8;  // 8 bf16
typedef __attribute__((ext_vector_type(4))) float f32x4;

#define STR 68   // fp32 LDS row stride (dwords)
#define HS  72   // bf16 LDS row stride (shorts) for A-layout H

__device__ __forceinline__ short f2bs(float x) {
    __hip_bfloat16 h = __float2bfloat16(x);
    return __builtin_bit_cast(short, h);
}

__global__ void transpose_wk(const float* __restrict__ Wk, float* __restrict__ WkT) {
    // block c transposes column c: WkT[c][g] = Wk[g][c]; write coalesced.
    const int c = blockIdx.x;
    const int g = threadIdx.x;
    WkT[c * 64 + g] = Wk[g * 64 + c];
}

__global__ __launch_bounds__(256, 4)
void ego_attn_kernel(const float* __restrict__ x,
                     const float* __restrict__ ego_w0, const float* __restrict__ ego_b0,
                     const float* __restrict__ ego_w1, const float* __restrict__ ego_b1,
                     const float* __restrict__ oth_w0, const float* __restrict__ oth_b0,
                     const float* __restrict__ oth_w1, const float* __restrict__ oth_b1,
                     const float* __restrict__ Wk, const float* __restrict__ WkT,
                     const float* __restrict__ Wv,
                     const float* __restrict__ Wq, const float* __restrict__ Wc,
                     float* __restrict__ out, int batches_per_block, int use_wkt)
{
    __shared__ __align__(16) short Ha[64 * HS];     // H bf16, A-layout rows
    __shared__ __align__(16) float Yb[64 * STR];    // input_all fp32 (row0 = ego)
    __shared__ __align__(16) float hegob[64];       // ego layer-1 output
    __shared__ __align__(16) float kqb[4 * STR];    // per-head Wk.q
    __shared__ __align__(16) float pbuf[4 * STR];   // per-head softmax probs
    __shared__ __align__(16) float pYb[4 * STR];    // per-head p.Y
    __shared__ __align__(16) float obuf[64];        // attention output (leader)
    __shared__ float b1l[64];                       // oth_b1 (for MFMA cols)

    const int tid = threadIdx.x;
    const int wv  = tid >> 6;                                  // wave id
    const int wvu = __builtin_amdgcn_readfirstlane(wv);        // provably uniform
    const int f   = tid & 63;     // lane = feature column / entity
    const int lg  = f >> 4;       // lane quad
    const int ln  = f & 15;

    // ---- persistent per-lane weights ----
    float w0o[7], w0e[7];
#pragma unroll
    for (int i = 0; i < 7; ++i) {
        w0o[i] = oth_w0[i * 64 + f];
        w0e[i] = ego_w0[i * 64 + f];
    }
    const float b0o = oth_b0[f], b0e = ego_b0[f], b1e = ego_b1[f];
    if (tid < 64) b1l[tid] = oth_b1[tid];
    if (wvu == 0) Ha[f] = 0;      // row 0 never written again (ego path separate)

    // oth_w1 as MFMA B-frags: lane holds B[k=(lg*8+j)+32kc][n=16ct+ln]
    short8 bfr[2][4];
#pragma unroll
    for (int kc = 0; kc < 2; ++kc)
#pragma unroll
        for (int ct = 0; ct < 4; ++ct) {
            short8 v;
#pragma unroll
            for (int j = 0; j < 8; ++j) {
                const int k = kc * 32 + lg * 8 + j;
                v[j] = f2bs(oth_w1[k * 64 + ct * 16 + ln]);
            }
            bfr[kc][ct] = v;
        }
    __syncthreads();   // b1l / Ha row-0 visible

    for (int bi = 0; bi < batches_per_block; ++bi) {
        const int b = blockIdx.x * batches_per_block + bi;
        const float* xb  = x + (size_t)b * 448;       // uniform base
        const float* xbw = xb + wvu * 112;            // this wave's 16 rows
        const bool isL = (wv == (bi & 3));            // rotating leader wave

        // per-lane mask value for entity f (one scattered load, hoisted early)
        const float xmask = xb[f * 7];

        // leader: ego layer-1 (row 0; x via uniform scalar loads)
        if (isL) {
            float a = b0e;
#pragma unroll
            for (int i = 0; i < 7; ++i) a = fmaf(xb[i], w0e[i], a);
            hegob[f] = fmaxf(a, 0.f);
        }
        // P1: layer-1 for own band -> Ha.  x operands are wave-uniform ->
        // scalar (SMEM) loads; no LDS staging at all.
#pragma unroll 4
        for (int er = 0; er < 16; ++er) {
            const int e = wvu * 16 + er;
            if (e == 0) continue;            // uniform skip
            float a = b0o;
#pragma unroll
            for (int i = 0; i < 7; ++i) a = fmaf(xbw[er * 7 + i], w0o[i], a);
            Ha[e * HS + f] = f2bs(fmaxf(a, 0.f));
        }
        // leader: ego layer-2 (residual stays in reg, publish Yb row 0)
        float ego_f = 0.f;
        if (isL) {
            float a = b1e;
#pragma unroll 8
            for (int j = 0; j < 64; ++j) a = fmaf(hegob[j], ego_w1[j * 64 + f], a);
            ego_f = fmaxf(a, 0.f);
            Yb[f] = ego_f;
        }
        // P2: MFMA band: Y[16wv..+16][:] = relu(H @ oth_w1 + b1)
        {
            const int eb = wvu * 16;
            const short8 a0 = *(const short8*)&Ha[(eb + ln) * HS + lg * 8];
            const short8 a1 = *(const short8*)&Ha[(eb + ln) * HS + lg * 8 + 32];
#pragma unroll
            for (int ct = 0; ct < 4; ++ct) {
                const float bv = b1l[ct * 16 + ln];
                f32x4 c = {bv, bv, bv, bv};
                c = __builtin_amdgcn_mfma_f32_16x16x32_bf16(a0, bfr[0][ct], c, 0, 0, 0);
                c = __builtin_amdgcn_mfma_f32_16x16x32_bf16(a1, bfr[1][ct], c, 0, 0, 0);
#pragma unroll
                for (int r = 0; r < 4; ++r) {
                    const int e = eb + lg * 4 + r;     // C-layout row
                    if (e != 0) Yb[e * STR + ct * 16 + ln] = fmaxf(c[r], 0.f);
                }
            }
        }
        __syncthreads();   // B3: all Yb rows (incl. ego row 0) visible

        // q[f] = ego . Wq[:,f]   (redundant per wave; Yb row 0 broadcast reads)
        float qf = 0.f;
#pragma unroll 4
        for (int j4 = 0; j4 < 16; ++j4) {
            const float4 y = *(const float4*)&Yb[4 * j4];
            qf = fmaf(y.x, Wq[(4 * j4 + 0) * 64 + f], qf);
            qf = fmaf(y.y, Wq[(4 * j4 + 1) * 64 + f], qf);
            qf = fmaf(y.z, Wq[(4 * j4 + 2) * 64 + f], qf);
            qf = fmaf(y.w, Wq[(4 * j4 + 3) * 64 + f], qf);
        }
        // kq_h[f] = sum_d Wk[f][16h+d] q[16h+d]  (h = wv; q via shfl).
        // WkT path: lane-coalesced loads from the ws transpose.
        {
            float a = 0.f;
            if (use_wkt) {
#pragma unroll
                for (int d = 0; d < 16; ++d) {
                    const float qd = __shfl(qf, wvu * 16 + d);
                    a = fmaf(WkT[(wvu * 16 + d) * 64 + f], qd, a);
                }
            } else {
#pragma unroll
                for (int d = 0; d < 16; ++d) {
                    const float qd = __shfl(qf, wvu * 16 + d);
                    a = fmaf(Wk[f * 64 + wvu * 16 + d], qd, a);
                }
            }
            kqb[wvu * STR + f] = a;   // wave-own row; read back below
        }
        // scores + softmax: lane = entity e, head = wv
        {
            const int e = f;
            float s = 0.f;
#pragma unroll 4
            for (int q4 = 0; q4 < 16; ++q4) {
                const float4 yv = *(const float4*)&Yb[e * STR + 4 * q4];
                const float4 kv = *(const float4*)&kqb[wvu * STR + 4 * q4];
                s = fmaf(yv.x, kv.x, s); s = fmaf(yv.y, kv.y, s);
                s = fmaf(yv.z, kv.z, s); s = fmaf(yv.w, kv.w, s);
            }
            s *= 0.25f;                              // 1/sqrt(16)
            if (xmask < 0.5f) s = -1e9f;             // absent-entity mask
            float m = s;
#pragma unroll
            for (int o = 32; o; o >>= 1) m = fmaxf(m, __shfl_xor(m, o));
            const float p = __expf(s - m);
            float sm = p;
#pragma unroll
            for (int o = 32; o; o >>= 1) sm += __shfl_xor(sm, o);
            pbuf[wvu * STR + e] = p / sm;
        }
        // pY[h][f] = sum_e p[h][e] Y[e][f]
        {
            float a = 0.f;
#pragma unroll 4
            for (int e4 = 0; e4 < 16; ++e4) {
                const float4 pv = *(const float4*)&pbuf[wvu * STR + 4 * e4];
                a = fmaf(pv.x, Yb[(4 * e4 + 0) * STR + f], a);
                a = fmaf(pv.y, Yb[(4 * e4 + 1) * STR + f], a);
                a = fmaf(pv.z, Yb[(4 * e4 + 2) * STR + f], a);
                a = fmaf(pv.w, Yb[(4 * e4 + 3) * STR + f], a);
            }
            pYb[wvu * STR + f] = a;
        }
        __syncthreads();   // B4: pYb complete

        // leader tail: out64 = pY @ Wv (head-sliced), result = out @ Wc + res
        if (isL) {
            const int hf = f >> 4;
            float o = 0.f;
#pragma unroll 8
            for (int j = 0; j < 64; ++j)
                o = fmaf(pYb[hf * STR + j], Wv[j * 64 + f], o);
            obuf[f] = o;
            float r = 0.f;
#pragma unroll 8
            for (int j = 0; j < 64; ++j)
                r = fmaf(obuf[j], Wc[j * 64 + f], r);
            out[(size_t)b * 64 + f] = (r + ego_f) * 0.5f;
        }
        // no end barrier: next batch's cross-wave reads are fenced by its B3,
        // which the leader joins only after finishing this tail.
    }
}

extern "C" void kernel_launch(void* const* d_in, const int* in_sizes, int n_in,
                              void* d_out, int out_size, void* d_ws, size_t ws_size,
                              hipStream_t stream) {
    const float* x      = (const float*)d_in[0];
    const float* ego_w0 = (const float*)d_in[1];
    const float* ego_b0 = (const float*)d_in[2];
    const float* ego_w1 = (const float*)d_in[3];
    const float* ego_b1 = (const float*)d_in[4];
    const float* oth_w0 = (const float*)d_in[5];
    const float* oth_b0 = (const float*)d_in[6];
    const float* oth_w1 = (const float*)d_in[7];
    const float* oth_b1 = (const float*)d_in[8];
    const float* Wk     = (const float*)d_in[9];
    const float* Wv     = (const float*)d_in[10];
    const float* Wq     = (const float*)d_in[11];
    const float* Wc     = (const float*)d_in[12];

    float* WkT = (float*)d_ws;
    const int use_wkt = (ws_size >= 64 * 64 * sizeof(float)) ? 1 : 0;
    if (use_wkt) {
        transpose_wk<<<64, 64, 0, stream>>>(Wk, WkT);
    }

    const int BPB = 8;                  // 8192 batches / 1024 blocks -> 4 blocks/CU
    ego_attn_kernel<<<1024, 256, 0, stream>>>(
        x, ego_w0, ego_b0, ego_w1, ego_b1,
        oth_w0, oth_b0, oth_w1, oth_b1,
        Wk, WkT, Wv, Wq, Wc,
        (float*)d_out, BPB, use_wkt);
}

// Round 5
// 134.482 us; speedup vs baseline: 3.0490x; 3.0490x over previous
//
#include <hip/hip_runtime.h>
#include <hip/hip_bf16.h>

// EgoAttentionNetwork: B=8192, E=64, F_IN=7, D=64, H=4, HD=16. fp32 in/out.
// Round 5: full restructure — one wave per batch, zero cross-wave traffic.
// Every matmul-shaped phase on MFMA 16x16x32_bf16 (fp32 accumulate):
//   P1: H  = relu(X(64x7->pad32) @ W0 + b0)        16 MFMA
//   P2: Y  = relu(H @ W1 + b1)                     32 MFMA   (row0 <- ego MLP, VALU)
//   P4: S  = Y @ KQ^T    (N=16, heads 0..3 real)    8 MFMA
//   P5: pY = P @ Y                                  8 MFMA
// Layout transforms (C-layout -> A-layout) via wave-local LDS round-trips.
// Serial matvecs (ego MLP, q, kq, o64, result) via v_readlane broadcasts
// (fully unrolled => constant lane => no ds_bpermute) + coalesced weight loads.
// Block = 64 (1 wave), grid = 8192, LDS ~15 KB/block -> ~10 waves/CU.

typedef __attribute__((ext_vector_type(8))) short short8;   // 8 bf16
typedef __attribute__((ext_vector_type(4))) short short4b;  // 4 bf16
typedef __attribute__((ext_vector_type(4))) float f32x4;

#define SY 72   // short stride for hy/kqt/pa rows (16B-aligned, de-conflicted)

__device__ __forceinline__ short f2bs(float x) {
    __hip_bfloat16 h = __float2bfloat16(x);
    return __builtin_bit_cast(short, h);
}
__device__ __forceinline__ float bs2f(short s) {
    __hip_bfloat16 h = __builtin_bit_cast(__hip_bfloat16, s);
    return __bfloat162float(h);
}

__global__ void transpose_wk(const float* __restrict__ Wk, float* __restrict__ WkT) {
    const int c = blockIdx.x;
    const int g = threadIdx.x;
    WkT[c * 64 + g] = Wk[g * 64 + c];   // WkT[c][g] = Wk[g][c], coalesced write
}

__global__ __launch_bounds__(64, 2)
void ego_attn_kernel(const float* __restrict__ x,
                     const float* __restrict__ ego_w0, const float* __restrict__ ego_b0,
                     const float* __restrict__ ego_w1, const float* __restrict__ ego_b1,
                     const float* __restrict__ oth_w0, const float* __restrict__ oth_b0,
                     const float* __restrict__ oth_w1, const float* __restrict__ oth_b1,
                     const float* __restrict__ Wk, const float* __restrict__ WkT,
                     const float* __restrict__ Wv,
                     const float* __restrict__ Wq, const float* __restrict__ Wc,
                     float* __restrict__ out, int use_wkt)
{
    __shared__ __align__(16) short hy[64 * SY];   // H, then Y (row-major bf16)
    __shared__ __align__(16) short kqt[16 * SY];  // KQt[h][f] (rows h>=4 garbage, quarantined)
    __shared__ __align__(16) short pa[16 * SY];   // Pa[h][e]  (rows h>=4 garbage, quarantined)
    __shared__ __align__(16) float mb[64];        // x[e][0] per entity
    __shared__ __align__(16) short pyb[4 * 68];   // pY bf16 [h][f]
    __shared__ __align__(16) float ob[64];        // o64

    const int lane = threadIdx.x;
    const int lg = lane >> 4, ln = lane & 15;
    const int b = blockIdx.x;
    const float* xb = x + (size_t)b * 448;

    // ---- phase 0: x loads ----
    mb[lane] = xb[lane * 7];                      // mask column (entity = lane)

    float x0[7] = {0, 0, 0, 0, 0, 0, 0};          // row 0 of x (valid in lane 0)
    short8 xa[4];                                 // A-frags of X (k<7 real, rest 0)
#pragma unroll
    for (int mt = 0; mt < 4; ++mt) {
        short8 v = {0, 0, 0, 0, 0, 0, 0, 0};
        if (lg == 0) {
            const float* xr = xb + (mt * 16 + ln) * 7;
            float t[7];
#pragma unroll
            for (int i = 0; i < 7; ++i) t[i] = xr[i];
            if (mt == 0) {
#pragma unroll
                for (int i = 0; i < 7; ++i) x0[i] = t[i];
            }
#pragma unroll
            for (int i = 0; i < 7; ++i) v[i] = f2bs(t[i]);
        }
        xa[mt] = v;
    }

    // ---- per-wave weight fragments ----
    short8 w0f[4];                                // W0 B-frags (k<7 real, rest 0)
#pragma unroll
    for (int ct = 0; ct < 4; ++ct) {
        short8 v = {0, 0, 0, 0, 0, 0, 0, 0};
        if (lg == 0) {
#pragma unroll
            for (int j = 0; j < 7; ++j) v[j] = f2bs(oth_w0[j * 64 + ct * 16 + ln]);
        }
        w0f[ct] = v;
    }
    short8 w1f[2][4];                             // W1 B-frags
#pragma unroll
    for (int kc = 0; kc < 2; ++kc)
#pragma unroll
        for (int ct = 0; ct < 4; ++ct) {
            short8 v;
#pragma unroll
            for (int j = 0; j < 8; ++j)
                v[j] = f2bs(oth_w1[(kc * 32 + lg * 8 + j) * 64 + ct * 16 + ln]);
            w1f[kc][ct] = v;
        }
    float b0v[4], b1v[4];
#pragma unroll
    for (int ct = 0; ct < 4; ++ct) {
        b0v[ct] = oth_b0[ct * 16 + ln];
        b1v[ct] = oth_b1[ct * 16 + ln];
    }
    const float b0e = ego_b0[lane], b1e = ego_b1[lane];
    float w0e[7];
#pragma unroll
    for (int i = 0; i < 7; ++i) w0e[i] = ego_w0[i * 64 + lane];

    // ---- ego layer-1 (VALU, readlane broadcasts of x row 0) ----
    float acc = b0e;
#pragma unroll
    for (int i = 0; i < 7; ++i) acc = fmaf(__shfl(x0[i], 0), w0e[i], acc);
    const float hego = fmaxf(acc, 0.f);

    // ---- P1: H = relu(X @ W0 + b0) -> hy (row 0 garbage, fixed later) ----
#pragma unroll
    for (int mt = 0; mt < 4; ++mt)
#pragma unroll
        for (int ct = 0; ct < 4; ++ct) {
            f32x4 c = {b0v[ct], b0v[ct], b0v[ct], b0v[ct]};
            c = __builtin_amdgcn_mfma_f32_16x16x32_bf16(xa[mt], w0f[ct], c, 0, 0, 0);
#pragma unroll
            for (int r = 0; r < 4; ++r)
                hy[(mt * 16 + lg * 4 + r) * SY + ct * 16 + ln] = f2bs(fmaxf(c[r], 0.f));
        }
    __syncthreads();

    // ---- read H A-frags before overwriting hy with Y ----
    short8 a2[4][2];
#pragma unroll
    for (int mt = 0; mt < 4; ++mt)
#pragma unroll
        for (int kc = 0; kc < 2; ++kc)
            a2[mt][kc] = *(const short8*)&hy[(mt * 16 + ln) * SY + kc * 32 + lg * 8];
    __syncthreads();

    // ---- ego layer-2 (VALU) ----
    acc = b1e;
#pragma unroll
    for (int j = 0; j < 64; ++j)
        acc = fmaf(__shfl(hego, j), ego_w1[j * 64 + lane], acc);
    const float ego = fmaxf(acc, 0.f);

    // ---- P2: Y = relu(H @ W1 + b1) -> hy; then row 0 <- ego ----
#pragma unroll
    for (int ct = 0; ct < 4; ++ct)
#pragma unroll
        for (int mt = 0; mt < 4; ++mt) {
            f32x4 c = {b1v[ct], b1v[ct], b1v[ct], b1v[ct]};
            c = __builtin_amdgcn_mfma_f32_16x16x32_bf16(a2[mt][0], w1f[0][ct], c, 0, 0, 0);
            c = __builtin_amdgcn_mfma_f32_16x16x32_bf16(a2[mt][1], w1f[1][ct], c, 0, 0, 0);
#pragma unroll
            for (int r = 0; r < 4; ++r)
                hy[(mt * 16 + lg * 4 + r) * SY + ct * 16 + ln] = f2bs(fmaxf(c[r], 0.f));
        }
    hy[lane] = f2bs(ego);                         // Y row 0 = ego

    // ---- q = ego @ Wq ; kq_h = Wk_h^T q (readlane broadcasts) ----
    float qf = 0.f;
#pragma unroll
    for (int j = 0; j < 64; ++j)
        qf = fmaf(__shfl(ego, j), Wq[j * 64 + lane], qf);
    float kqh[4] = {0.f, 0.f, 0.f, 0.f};
    if (use_wkt) {
#pragma unroll
        for (int j = 0; j < 64; ++j) {
            const float qj = __shfl(qf, j);
            kqh[j >> 4] = fmaf(WkT[j * 64 + lane], qj, kqh[j >> 4]);
        }
    } else {
#pragma unroll
        for (int j = 0; j < 64; ++j) {
            const float qj = __shfl(qf, j);
            kqh[j >> 4] = fmaf(Wk[lane * 64 + j], qj, kqh[j >> 4]);
        }
    }
#pragma unroll
    for (int h = 0; h < 4; ++h) kqt[h * SY + lane] = f2bs(kqh[h]);
    __syncthreads();

    // ---- P4: S = Y @ KQ^T (M=64 e, N=16, K=64); softmax per head h=ln ----
    short8 ya[4][2];
#pragma unroll
    for (int mt = 0; mt < 4; ++mt)
#pragma unroll
        for (int kc = 0; kc < 2; ++kc)
            ya[mt][kc] = *(const short8*)&hy[(mt * 16 + ln) * SY + kc * 32 + lg * 8];
    short8 kb[2];
#pragma unroll
    for (int kc = 0; kc < 2; ++kc)
        kb[kc] = *(const short8*)&kqt[ln * SY + kc * 32 + lg * 8];

    float sv[16];
    float m = -3e38f;
#pragma unroll
    for (int mt = 0; mt < 4; ++mt) {
        f32x4 c = {0.f, 0.f, 0.f, 0.f};
        c = __builtin_amdgcn_mfma_f32_16x16x32_bf16(ya[mt][0], kb[0], c, 0, 0, 0);
        c = __builtin_amdgcn_mfma_f32_16x16x32_bf16(ya[mt][1], kb[1], c, 0, 0, 0);
        const float4 mk = *(const float4*)&mb[mt * 16 + lg * 4];
        const float mkv[4] = {mk.x, mk.y, mk.z, mk.w};
#pragma unroll
        for (int r = 0; r < 4; ++r) {
            float s = c[r] * 0.25f;                       // 1/sqrt(HD=16)
            if (mkv[r] < 0.5f) s = -1e9f;                 // absent-entity mask
            sv[mt * 4 + r] = s;
            m = fmaxf(m, s);
        }
    }
    m = fmaxf(m, __shfl_xor(m, 16));
    m = fmaxf(m, __shfl_xor(m, 32));
    float sum = 0.f;
#pragma unroll
    for (int k = 0; k < 16; ++k) { sv[k] = __expf(sv[k] - m); sum += sv[k]; }
    sum += __shfl_xor(sum, 16);
    sum += __shfl_xor(sum, 32);
    const float inv = 1.f / sum;
#pragma unroll
    for (int mt = 0; mt < 4; ++mt) {
        short4b pk;
#pragma unroll
        for (int r = 0; r < 4; ++r) pk[r] = f2bs(sv[mt * 4 + r] * inv);
        *(short4b*)&pa[ln * SY + mt * 16 + lg * 4] = pk;   // Pa[h=ln][e]
    }
    __syncthreads();

    // ---- P5: pY = P @ Y (M=16, N=64, K=64); rows h<4 real ----
    short8 pf[2];
#pragma unroll
    for (int kc = 0; kc < 2; ++kc)
        pf[kc] = *(const short8*)&pa[ln * SY + kc * 32 + lg * 8];
#pragma unroll
    for (int ct = 0; ct < 4; ++ct) {
        f32x4 c = {0.f, 0.f, 0.f, 0.f};
#pragma unroll
        for (int kc = 0; kc < 2; ++kc) {
            short8 yv;
#pragma unroll
            for (int j = 0; j < 8; ++j)
                yv[j] = hy[(kc * 32 + lg * 8 + j) * SY + ct * 16 + ln];  // Y column reads
            c = __builtin_amdgcn_mfma_f32_16x16x32_bf16(pf[kc], yv, c, 0, 0, 0);
        }
        if (lg == 0) {
#pragma unroll
            for (int r = 0; r < 4; ++r) pyb[r * 68 + ct * 16 + ln] = f2bs(c[r]);
        }
    }
    __syncthreads();

    // ---- o64[c] = sum_f pY[c>>4][f] Wv[f][c] ----
    const int h = lane >> 4;
    float o = 0.f;
#pragma unroll
    for (int f4 = 0; f4 < 16; ++f4) {
        const short4b pv = *(const short4b*)&pyb[h * 68 + f4 * 4];
#pragma unroll
        for (int u = 0; u < 4; ++u)
            o = fmaf(bs2f(pv[u]), Wv[(f4 * 4 + u) * 64 + lane], o);
    }
    ob[lane] = o;
    __syncthreads();

    // ---- result = o64 @ Wc + ego, * 0.5 ----
    float r2 = 0.f;
#pragma unroll
    for (int j4 = 0; j4 < 16; ++j4) {
        const float4 ov = *(const float4*)&ob[j4 * 4];
        const float ovv[4] = {ov.x, ov.y, ov.z, ov.w};
#pragma unroll
        for (int u = 0; u < 4; ++u)
            r2 = fmaf(ovv[u], Wc[(j4 * 4 + u) * 64 + lane], r2);
    }
    out[(size_t)b * 64 + lane] = (r2 + ego) * 0.5f;
}

extern "C" void kernel_launch(void* const* d_in, const int* in_sizes, int n_in,
                              void* d_out, int out_size, void* d_ws, size_t ws_size,
                              hipStream_t stream) {
    const float* x      = (const float*)d_in[0];
    const float* ego_w0 = (const float*)d_in[1];
    const float* ego_b0 = (const float*)d_in[2];
    const float* ego_w1 = (const float*)d_in[3];
    const float* ego_b1 = (const float*)d_in[4];
    const float* oth_w0 = (const float*)d_in[5];
    const float* oth_b0 = (const float*)d_in[6];
    const float* oth_w1 = (const float*)d_in[7];
    const float* oth_b1 = (const float*)d_in[8];
    const float* Wk     = (const float*)d_in[9];
    const float* Wv     = (const float*)d_in[10];
    const float* Wq     = (const float*)d_in[11];
    const float* Wc     = (const float*)d_in[12];

    float* WkT = (float*)d_ws;
    const int use_wkt = (ws_size >= 64 * 64 * sizeof(float)) ? 1 : 0;
    if (use_wkt) transpose_wk<<<64, 64, 0, stream>>>(Wk, WkT);

    ego_attn_kernel<<<8192, 64, 0, stream>>>(
        x, ego_w0, ego_b0, ego_w1, ego_b1,
        oth_w0, oth_b0, oth_w1, oth_b1,
        Wk, WkT, Wv, Wq, Wc,
        (float*)d_out, use_wkt);
}

// Round 6
// 121.981 us; speedup vs baseline: 3.3614x; 1.1025x over previous
//
#include <hip/hip_runtime.h>
#include <hip/hip_bf16.h>

// EgoAttentionNetwork: B=8192, E=64, F_IN=7, D=64, H=4, HD=16. fp32 in/out.
// Round 6: all phases on MFMA; tail weights pre-packed bf16-transposed in d_ws.
//  - prologue pack_ws: G (fused Wq.Wk per head), ego_w0/w1, oth_w0/w1, Wv, Wc,
//    each stored [n][k] (transposed) so B-frags are single global_load_dwordx4.
//  - main kernel: block=64 (1 wave), grid=2048, 4 batches/wave, no cross-wave
//    traffic. Chain (egoL1 -> egoL2 -> KQ=Ego@G^T) = M=16 MFMAs per 4 batches.
//    Per batch: P1(16), P2(32), S(8), pY(8) MFMAs as round 5.
//    Tail: o64 = pY@Wv (head-sliced), result = o64@Wc + ego residual (in regs).
//  - garbage MFMA rows/cols quarantined via (&3) replication (finite copies).

typedef __attribute__((ext_vector_type(8))) short short8;   // 8 bf16
typedef __attribute__((ext_vector_type(4))) short short4b;  // 4 bf16
typedef __attribute__((ext_vector_type(4))) float f32x4;

#define SY 72          // u16 row stride for LDS buffers

// ws offsets in u16 units (total 33792 u16 = 67584 B)
#define WS_G    0      // [256][64]  G[(h*64+f)][j]
#define WS_EGW0 16384  // [64][8]    ego_w0^T (k<7 real, k=7 zero)
#define WS_EGW1 16896  // [64][64]   ego_w1^T
#define WS_WVT  20992  // [64][64]   Wv^T
#define WS_WCT  25088  // [64][64]   Wc^T
#define WS_W0T  29184  // [64][8]    oth_w0^T
#define WS_W1T  29696  // [64][64]   oth_w1^T

__device__ __forceinline__ short f2bs(float x) {
    __hip_bfloat16 h = __float2bfloat16(x);
    return __builtin_bit_cast(short, h);
}
__device__ __forceinline__ unsigned short f2u(float x) {
    __hip_bfloat16 h = __float2bfloat16(x);
    return __builtin_bit_cast(unsigned short, h);
}
__device__ __forceinline__ short8 ldws8(const unsigned short* p) {
    return *(const short8*)p;   // 16B-aligned -> global_load_dwordx4
}

__global__ void pack_ws(const float* __restrict__ ego_w0, const float* __restrict__ ego_w1,
                        const float* __restrict__ oth_w0, const float* __restrict__ oth_w1,
                        const float* __restrict__ Wk, const float* __restrict__ Wv,
                        const float* __restrict__ Wq, const float* __restrict__ Wc,
                        unsigned short* __restrict__ ws) {
    const int blk = blockIdx.x, t = threadIdx.x;
    if (blk < 256) {
        // G[n=(h*64+f)][j] = sum_d Wq[j][16h+d] * Wk[f][16h+d]
        const int n = blk, h = n >> 6, f = n & 63, j = t;
        float a = 0.f;
#pragma unroll
        for (int d = 0; d < 16; ++d)
            a = fmaf(Wq[j * 64 + h * 16 + d], Wk[f * 64 + h * 16 + d], a);
        ws[WS_G + n * 64 + j] = f2u(a);
    } else {
        const int n = blk - 256, k = t;    // n = output col, k = contraction idx
        ws[WS_EGW1 + n * 64 + k] = f2u(ego_w1[k * 64 + n]);
        ws[WS_WVT  + n * 64 + k] = f2u(Wv[k * 64 + n]);
        ws[WS_WCT  + n * 64 + k] = f2u(Wc[k * 64 + n]);
        ws[WS_W1T  + n * 64 + k] = f2u(oth_w1[k * 64 + n]);
        if (k < 8) {
            ws[WS_EGW0 + n * 8 + k] = (k < 7) ? f2u(ego_w0[k * 64 + n]) : 0;
            ws[WS_W0T  + n * 8 + k] = (k < 7) ? f2u(oth_w0[k * 64 + n]) : 0;
        }
    }
}

__global__ __launch_bounds__(64, 2)
void ego_attn_kernel(const float* __restrict__ x,
                     const float* __restrict__ ego_b0, const float* __restrict__ ego_b1,
                     const float* __restrict__ oth_b0, const float* __restrict__ oth_b1,
                     const unsigned short* __restrict__ ws,
                     float* __restrict__ out)
{
    __shared__ __align__(16) short hy[64 * SY];    // H then Y, row-major bf16
    __shared__ __align__(16) short chainbuf[4 * SY];
    __shared__ __align__(16) short kqb[16 * SY];   // row b*4+h : kq[b][h][f]*0.25
    __shared__ __align__(16) short pa[16 * SY];    // P[h][e] (rows h>=4 = copies)
    __shared__ __align__(16) short py[16 * SY];    // row h*4+b : pY[b][h][f]
    __shared__ __align__(16) short ob[4 * SY];     // o64 rows b
    __shared__ __align__(16) float mb[64];         // x[e][0] mask column

    const int lane = threadIdx.x;
    const int lg = lane >> 4, ln = lane & 15;
    const int gb = blockIdx.x * 4;                 // 4 batches per wave

    // ---- persistent frags (from ws, 16B vector loads) ----
    short8 w0f[4], w1f[2][4];
#pragma unroll
    for (int ct = 0; ct < 4; ++ct) {
        short8 z = {0, 0, 0, 0, 0, 0, 0, 0};
        w0f[ct] = (lg == 0) ? ldws8(ws + WS_W0T + (ct * 16 + ln) * 8) : z;
    }
#pragma unroll
    for (int kc = 0; kc < 2; ++kc)
#pragma unroll
        for (int ct = 0; ct < 4; ++ct)
            w1f[kc][ct] = ldws8(ws + WS_W1T + (ct * 16 + ln) * 64 + kc * 32 + lg * 8);
    float b0v[4], b1v[4], eb0v[4], eb1v[4];
#pragma unroll
    for (int ct = 0; ct < 4; ++ct) {
        b0v[ct]  = oth_b0[ct * 16 + ln];
        b1v[ct]  = oth_b1[ct * 16 + ln];
        eb0v[ct] = ego_b0[ct * 16 + ln];
        eb1v[ct] = ego_b1[ct * 16 + ln];
    }

    // ================= chain: egoL1 -> egoL2 -> KQ (all 4 batches) ==========
    short8 xea = {0, 0, 0, 0, 0, 0, 0, 0};        // A[m=b][k=i<7] = x_b row 0
    if (lg == 0 && ln < 4) {
        const float* xr = x + (size_t)(gb + ln) * 448;
#pragma unroll
        for (int i = 0; i < 7; ++i) xea[i] = f2bs(xr[i]);
    }
#pragma unroll
    for (int ct = 0; ct < 4; ++ct) {              // Hego = relu(x0 @ ego_w0 + b0)
        short8 z = {0, 0, 0, 0, 0, 0, 0, 0};
        const short8 bfr = (lg == 0) ? ldws8(ws + WS_EGW0 + (ct * 16 + ln) * 8) : z;
        f32x4 c = {eb0v[ct], eb0v[ct], eb0v[ct], eb0v[ct]};
        c = __builtin_amdgcn_mfma_f32_16x16x32_bf16(xea, bfr, c, 0, 0, 0);
        if (lg == 0) {
#pragma unroll
            for (int r = 0; r < 4; ++r)
                chainbuf[r * SY + ct * 16 + ln] = f2bs(fmaxf(c[r], 0.f));
        }
    }
    __syncthreads();
    short8 ha[2];
#pragma unroll
    for (int kc = 0; kc < 2; ++kc)
        ha[kc] = *(const short8*)&chainbuf[(ln & 3) * SY + kc * 32 + lg * 8];
    __syncthreads();

    float egoR[4][4];                              // Ego (post-relu), C-layout, lg==0 rows real
#pragma unroll
    for (int ct = 0; ct < 4; ++ct) {              // Ego = relu(Hego @ ego_w1 + b1)
        f32x4 c = {eb1v[ct], eb1v[ct], eb1v[ct], eb1v[ct]};
#pragma unroll
        for (int kc = 0; kc < 2; ++kc) {
            const short8 bfr = ldws8(ws + WS_EGW1 + (ct * 16 + ln) * 64 + kc * 32 + lg * 8);
            c = __builtin_amdgcn_mfma_f32_16x16x32_bf16(ha[kc], bfr, c, 0, 0, 0);
        }
#pragma unroll
        for (int r = 0; r < 4; ++r) egoR[ct][r] = fmaxf(c[r], 0.f);
    }
    if (lg == 0) {
#pragma unroll
        for (int ct = 0; ct < 4; ++ct)
#pragma unroll
            for (int r = 0; r < 4; ++r)
                chainbuf[r * SY + ct * 16 + ln] = f2bs(egoR[ct][r]);
    }
    __syncthreads();
    short8 ea[2];
#pragma unroll
    for (int kc = 0; kc < 2; ++kc)
        ea[kc] = *(const short8*)&chainbuf[(ln & 3) * SY + kc * 32 + lg * 8];

    // KQ[b][n=(h*64+f)] = sum_j Ego[b][j] G[n][j]; fold 0.25 score scale here
#pragma unroll
    for (int ctg = 0; ctg < 16; ++ctg) {
        f32x4 c = {0.f, 0.f, 0.f, 0.f};
#pragma unroll
        for (int kc = 0; kc < 2; ++kc) {
            const short8 bfr = ldws8(ws + WS_G + (ctg * 16 + ln) * 64 + kc * 32 + lg * 8);
            c = __builtin_amdgcn_mfma_f32_16x16x32_bf16(ea[kc], bfr, c, 0, 0, 0);
        }
        if (lg == 0) {
            const int h = ctg >> 2, fc = (ctg & 3) * 16 + ln;
#pragma unroll
            for (int r = 0; r < 4; ++r)
                kqb[(r * 4 + h) * SY + fc] = f2bs(c[r] * 0.25f);
        }
    }
    __syncthreads();

    // ================= per-batch: P1, P2, S+softmax, pY ======================
#pragma unroll
    for (int i = 0; i < 4; ++i) {
        const float* xb = x + (size_t)(gb + i) * 448;
        mb[lane] = xb[lane * 7];                  // mask column (e = lane)

        short8 xa[4];                             // A[m=e][k=i<7]
#pragma unroll
        for (int mt = 0; mt < 4; ++mt) {
            short8 v = {0, 0, 0, 0, 0, 0, 0, 0};
            if (lg == 0) {
                const float* xr = xb + (mt * 16 + ln) * 7;
#pragma unroll
                for (int k = 0; k < 7; ++k) v[k] = f2bs(xr[k]);
            }
            xa[mt] = v;
        }
        // P1: H = relu(X @ W0 + b0)
#pragma unroll
        for (int mt = 0; mt < 4; ++mt)
#pragma unroll
            for (int ct = 0; ct < 4; ++ct) {
                f32x4 c = {b0v[ct], b0v[ct], b0v[ct], b0v[ct]};
                c = __builtin_amdgcn_mfma_f32_16x16x32_bf16(xa[mt], w0f[ct], c, 0, 0, 0);
#pragma unroll
                for (int r = 0; r < 4; ++r)
                    hy[(mt * 16 + lg * 4 + r) * SY + ct * 16 + ln] = f2bs(fmaxf(c[r], 0.f));
            }
        __syncthreads();
        short8 a2[4][2];
#pragma unroll
        for (int mt = 0; mt < 4; ++mt)
#pragma unroll
            for (int kc = 0; kc < 2; ++kc)
                a2[mt][kc] = *(const short8*)&hy[(mt * 16 + ln) * SY + kc * 32 + lg * 8];
        __syncthreads();
        // P2: Y = relu(H @ W1 + b1); then row 0 <- ego
#pragma unroll
        for (int ct = 0; ct < 4; ++ct)
#pragma unroll
            for (int mt = 0; mt < 4; ++mt) {
                f32x4 c = {b1v[ct], b1v[ct], b1v[ct], b1v[ct]};
                c = __builtin_amdgcn_mfma_f32_16x16x32_bf16(a2[mt][0], w1f[0][ct], c, 0, 0, 0);
                c = __builtin_amdgcn_mfma_f32_16x16x32_bf16(a2[mt][1], w1f[1][ct], c, 0, 0, 0);
#pragma unroll
                for (int r = 0; r < 4; ++r)
                    hy[(mt * 16 + lg * 4 + r) * SY + ct * 16 + ln] = f2bs(fmaxf(c[r], 0.f));
            }
        if (lg == 0) {
#pragma unroll
            for (int ct = 0; ct < 4; ++ct)
                hy[ct * 16 + ln] = f2bs(egoR[ct][i]);   // Y row 0 = ego_i
        }
        __syncthreads();
        // S = Y @ kq_i^T (N=16: n=h, cols >=4 are copies); softmax per head
        short8 ya[4][2];
#pragma unroll
        for (int mt = 0; mt < 4; ++mt)
#pragma unroll
            for (int kc = 0; kc < 2; ++kc)
                ya[mt][kc] = *(const short8*)&hy[(mt * 16 + ln) * SY + kc * 32 + lg * 8];
        short8 kb[2];
#pragma unroll
        for (int kc = 0; kc < 2; ++kc)
            kb[kc] = *(const short8*)&kqb[(i * 4 + (ln & 3)) * SY + kc * 32 + lg * 8];

        float sv[16];
        float m = -3e38f;
#pragma unroll
        for (int mt = 0; mt < 4; ++mt) {
            f32x4 c = {0.f, 0.f, 0.f, 0.f};
            c = __builtin_amdgcn_mfma_f32_16x16x32_bf16(ya[mt][0], kb[0], c, 0, 0, 0);
            c = __builtin_amdgcn_mfma_f32_16x16x32_bf16(ya[mt][1], kb[1], c, 0, 0, 0);
            const float4 mk = *(const float4*)&mb[mt * 16 + lg * 4];
            const float mkv[4] = {mk.x, mk.y, mk.z, mk.w};
#pragma unroll
            for (int r = 0; r < 4; ++r) {
                float s = c[r];                          // 0.25 folded into kqb
                if (mkv[r] < 0.5f) s = -1e9f;
                sv[mt * 4 + r] = s;
                m = fmaxf(m, s);
            }
        }
        m = fmaxf(m, __shfl_xor(m, 16));
        m = fmaxf(m, __shfl_xor(m, 32));
        float sum = 0.f;
#pragma unroll
        for (int k = 0; k < 16; ++k) { sv[k] = __expf(sv[k] - m); sum += sv[k]; }
        sum += __shfl_xor(sum, 16);
        sum += __shfl_xor(sum, 32);
        const float inv = 1.f / sum;
#pragma unroll
        for (int mt = 0; mt < 4; ++mt) {
            short4b pk;
#pragma unroll
            for (int r = 0; r < 4; ++r) pk[r] = f2bs(sv[mt * 4 + r] * inv);
            *(short4b*)&pa[ln * SY + mt * 16 + lg * 4] = pk;   // P[h=ln][e]
        }
        __syncthreads();
        // pY = P @ Y  (M=16: m=h, rows >=4 copies)
        short8 pf[2];
#pragma unroll
        for (int kc = 0; kc < 2; ++kc)
            pf[kc] = *(const short8*)&pa[ln * SY + kc * 32 + lg * 8];
#pragma unroll
        for (int ct = 0; ct < 4; ++ct) {
            f32x4 c = {0.f, 0.f, 0.f, 0.f};
#pragma unroll
            for (int kc = 0; kc < 2; ++kc) {
                short8 yv;
#pragma unroll
                for (int j = 0; j < 8; ++j)
                    yv[j] = hy[(kc * 32 + lg * 8 + j) * SY + ct * 16 + ln];
                c = __builtin_amdgcn_mfma_f32_16x16x32_bf16(pf[kc], yv, c, 0, 0, 0);
            }
            if (lg == 0) {
#pragma unroll
                for (int r = 0; r < 4; ++r)
                    py[(r * 4 + i) * SY + ct * 16 + ln] = f2bs(c[r]);   // [h][b][f]
            }
        }
        __syncthreads();
    }

    // ================= tail: o64 = pY @ Wv (head-sliced), result ============
#pragma unroll
    for (int ct = 0; ct < 4; ++ct) {              // ct = head h; cols 16h..16h+16
        short8 af[2];
#pragma unroll
        for (int kc = 0; kc < 2; ++kc)
            af[kc] = *(const short8*)&py[(ct * 4 + (ln & 3)) * SY + kc * 32 + lg * 8];
        f32x4 c = {0.f, 0.f, 0.f, 0.f};
#pragma unroll
        for (int kc = 0; kc < 2; ++kc) {
            const short8 bfr = ldws8(ws + WS_WVT + (ct * 16 + ln) * 64 + kc * 32 + lg * 8);
            c = __builtin_amdgcn_mfma_f32_16x16x32_bf16(af[kc], bfr, c, 0, 0, 0);
        }
        if (lg == 0) {
#pragma unroll
            for (int r = 0; r < 4; ++r)
                ob[r * SY + ct * 16 + ln] = f2bs(c[r]);
        }
    }
    __syncthreads();
    short8 oa[2];
#pragma unroll
    for (int kc = 0; kc < 2; ++kc)
        oa[kc] = *(const short8*)&ob[(ln & 3) * SY + kc * 32 + lg * 8];
#pragma unroll
    for (int ct = 0; ct < 4; ++ct) {              // result = o64 @ Wc + ego, *0.5
        f32x4 c = {0.f, 0.f, 0.f, 0.f};
#pragma unroll
        for (int kc = 0; kc < 2; ++kc) {
            const short8 bfr = ldws8(ws + WS_WCT + (ct * 16 + ln) * 64 + kc * 32 + lg * 8);
            c = __builtin_amdgcn_mfma_f32_16x16x32_bf16(oa[kc], bfr, c, 0, 0, 0);
        }
        if (lg == 0) {
#pragma unroll
            for (int r = 0; r < 4; ++r)
                out[(size_t)(gb + r) * 64 + ct * 16 + ln] = (c[r] + egoR[ct][r]) * 0.5f;
        }
    }
}

extern "C" void kernel_launch(void* const* d_in, const int* in_sizes, int n_in,
                              void* d_out, int out_size, void* d_ws, size_t ws_size,
                              hipStream_t stream) {
    const float* x      = (const float*)d_in[0];
    const float* ego_w0 = (const float*)d_in[1];
    const float* ego_b0 = (const float*)d_in[2];
    const float* ego_w1 = (const float*)d_in[3];
    const float* ego_b1 = (const float*)d_in[4];
    const float* oth_w0 = (const float*)d_in[5];
    const float* oth_b0 = (const float*)d_in[6];
    const float* oth_w1 = (const float*)d_in[7];
    const float* oth_b1 = (const float*)d_in[8];
    const float* Wk     = (const float*)d_in[9];
    const float* Wv     = (const float*)d_in[10];
    const float* Wq     = (const float*)d_in[11];
    const float* Wc     = (const float*)d_in[12];

    unsigned short* ws = (unsigned short*)d_ws;   // needs 67584 B
    pack_ws<<<320, 64, 0, stream>>>(ego_w0, ego_w1, oth_w0, oth_w1,
                                    Wk, Wv, Wq, Wc, ws);
    ego_attn_kernel<<<2048, 64, 0, stream>>>(
        x, ego_b0, ego_b1, oth_b0, oth_b1, ws, (float*)d_out);
}